// Round 5
// baseline (281.765 us; speedup 1.0000x reference)
//
#include <hip/hip_runtime.h>
#include <hip/hip_bf16.h>

typedef __hip_bfloat16 bf16;
typedef __attribute__((ext_vector_type(8))) short short8;
typedef __attribute__((ext_vector_type(4))) short short4_t;
typedef __attribute__((ext_vector_type(4))) float f32x4;
typedef unsigned int u32;

#define MFMA16(a, b, c) __builtin_amdgcn_mfma_f32_16x16x32_bf16(a, b, c, 0, 0, 0)

static constexpr int S_ = 2048, D_ = 1024, M_ = 8192;
static constexpr size_t SZ = (size_t)M_ * D_;   // 8.39M elems
static constexpr size_t WSZ = (size_t)D_ * D_;  // 1.05M elems
static constexpr float QSCALE = 0.125f * 1.4426950408889634f;  // 1/sqrt(64) * log2(e)

__device__ __forceinline__ void gload16(void* lds, const void* g) {
  __builtin_amdgcn_global_load_lds((const __attribute__((address_space(1))) void*)g,
                                   (__attribute__((address_space(3))) void*)lds, 16, 0, 0);
}

__device__ __forceinline__ short4_t cvt4(const float4 v) {
  short4_t r;
  r[0] = (short)__bfloat16_as_ushort(__float2bfloat16(v.x));
  r[1] = (short)__bfloat16_as_ushort(__float2bfloat16(v.y));
  r[2] = (short)__bfloat16_as_ushort(__float2bfloat16(v.z));
  r[3] = (short)__bfloat16_as_ushort(__float2bfloat16(v.w));
  return r;
}

__device__ __forceinline__ u32 pk2(float a, float b) {
  return (u32)__bfloat16_as_ushort(__float2bfloat16(a)) |
         ((u32)__bfloat16_as_ushort(__float2bfloat16(b)) << 16);
}

__global__ __launch_bounds__(256) void cvt_f32_bf16(const float* __restrict__ in,
                                                    bf16* __restrict__ out, int n4) {
  int stride = gridDim.x * 256;
  for (int i = blockIdx.x * 256 + threadIdx.x; i < n4; i += stride) {
    float4 v = ((const float4*)in)[i];
    *(short4_t*)&out[(size_t)i * 4] = cvt4(v);
  }
}

// convert nseg weight matrices (1024x1024 f32) to bf16. segs 0-2 -> dqkv contiguous, seg 3 -> dwo.
__global__ __launch_bounds__(256) void cvt_w(const float* __restrict__ s0, const float* __restrict__ s1,
                                             const float* __restrict__ s2, const float* __restrict__ s3,
                                             bf16* __restrict__ dqkv, bf16* __restrict__ dwo, int nseg) {
  const int per = 1 << 18;  // WSZ/4 float4 per segment
  int total = nseg * per;
  for (int i = blockIdx.x * 256 + threadIdx.x; i < total; i += gridDim.x * 256) {
    int seg = i >> 18, off = i & (per - 1);
    const float* s = (seg == 0) ? s0 : (seg == 1) ? s1 : (seg == 2) ? s2 : s3;
    bf16* d = (seg < 3) ? (dqkv + ((size_t)seg << 20)) : dwo;
    float4 v = ((const float4*)s)[off];
    *(short4_t*)&d[(size_t)off * 4] = cvt4(v);
  }
}

// Fused QKV projection: by in [0,24): mat = by>>3 (0=Q,1=K,2=V), n0 = (by&7)*128.
// Q scaled by QSCALE; Q,K -> [B][H][S][64]; V -> [B][H][64][S] transposed.
__global__ __launch_bounds__(256) void qkv_gemm(const bf16* __restrict__ A,
                                                const bf16* __restrict__ Wqkv,
                                                bf16* __restrict__ QKV) {
  __shared__ __align__(16) bf16 lA[128 * 32];
  __shared__ __align__(16) bf16 lB[128 * 32];
  const int tid = threadIdx.x, lane = tid & 63, w = tid >> 6;
  const int wr = w >> 1, wc = w & 1;
  const int m0 = blockIdx.x * 128;
  const int mat = blockIdx.y >> 3, n0 = (blockIdx.y & 7) * 128;
  const bf16* W = Wqkv + (size_t)mat * WSZ;
  bf16* C = QKV + (size_t)mat * SZ;
  const int l15 = lane & 15, lg = lane >> 4;

  f32x4 zero = {0.f, 0.f, 0.f, 0.f};
  f32x4 acc[4][4];
#pragma unroll
  for (int i = 0; i < 4; i++)
#pragma unroll
    for (int j = 0; j < 4; j++) acc[i][j] = zero;

  for (int kt = 0; kt < 32; ++kt) {
    const int k0 = kt * 32;
#pragma unroll
    for (int i = 0; i < 2; ++i) {
      int c = i * 256 + tid;
      int row = c >> 2, col = (c & 3) * 8;
      gload16(&lA[c * 8], &A[(size_t)(m0 + row) * 1024 + k0 + col]);
      gload16(&lB[c * 8], &W[(size_t)(n0 + row) * 1024 + k0 + col]);
    }
    __syncthreads();

    short8 af[4], bfr[4];
#pragma unroll
    for (int mi = 0; mi < 4; mi++)
      af[mi] = *(const short8*)&lA[(wr * 64 + mi * 16 + l15) * 32 + lg * 8];
#pragma unroll
    for (int ni = 0; ni < 4; ni++)
      bfr[ni] = *(const short8*)&lB[(wc * 64 + ni * 16 + l15) * 32 + lg * 8];
#pragma unroll
    for (int mi = 0; mi < 4; mi++)
#pragma unroll
      for (int ni = 0; ni < 4; ni++) acc[mi][ni] = MFMA16(af[mi], bfr[ni], acc[mi][ni]);
    __syncthreads();
  }

  const float scale = (mat == 0) ? QSCALE : 1.0f;
#pragma unroll
  for (int mi = 0; mi < 4; mi++)
#pragma unroll
    for (int ni = 0; ni < 4; ni++)
#pragma unroll
      for (int r = 0; r < 4; r++) {
        int m = m0 + wr * 64 + mi * 16 + lg * 4 + r;
        int n = n0 + wc * 64 + ni * 16 + l15;
        int b = m >> 11, s = m & 2047, h = n >> 6, dh = n & 63;
        size_t idx = (mat < 2) ? (((size_t)((b << 4) + h) * 2048 + s) * 64 + dh)
                               : (((size_t)((b << 4) + h) * 64 + dh) * 2048 + s);
        C[idx] = __float2bfloat16(acc[mi][ni][r] * scale);
      }
}

// Output projection: C[m][n] f32 = sum_k AO[m][k] * Wo[n][k]
__global__ __launch_bounds__(256) void gemm_out(const bf16* __restrict__ A,
                                                const bf16* __restrict__ W,
                                                float* __restrict__ C) {
  __shared__ __align__(16) bf16 lA[128 * 32];
  __shared__ __align__(16) bf16 lB[128 * 32];
  const int tid = threadIdx.x, lane = tid & 63, w = tid >> 6;
  const int wr = w >> 1, wc = w & 1;
  const int m0 = blockIdx.x * 128, n0 = blockIdx.y * 128;
  const int l15 = lane & 15, lg = lane >> 4;

  f32x4 zero = {0.f, 0.f, 0.f, 0.f};
  f32x4 acc[4][4];
#pragma unroll
  for (int i = 0; i < 4; i++)
#pragma unroll
    for (int j = 0; j < 4; j++) acc[i][j] = zero;

  for (int kt = 0; kt < 32; ++kt) {
    const int k0 = kt * 32;
#pragma unroll
    for (int i = 0; i < 2; ++i) {
      int c = i * 256 + tid;
      int row = c >> 2, col = (c & 3) * 8;
      gload16(&lA[c * 8], &A[(size_t)(m0 + row) * 1024 + k0 + col]);
      gload16(&lB[c * 8], &W[(size_t)(n0 + row) * 1024 + k0 + col]);
    }
    __syncthreads();

    short8 af[4], bfr[4];
#pragma unroll
    for (int mi = 0; mi < 4; mi++)
      af[mi] = *(const short8*)&lA[(wr * 64 + mi * 16 + l15) * 32 + lg * 8];
#pragma unroll
    for (int ni = 0; ni < 4; ni++)
      bfr[ni] = *(const short8*)&lB[(wc * 64 + ni * 16 + l15) * 32 + lg * 8];
#pragma unroll
    for (int mi = 0; mi < 4; mi++)
#pragma unroll
      for (int ni = 0; ni < 4; ni++) acc[mi][ni] = MFMA16(af[mi], bfr[ni], acc[mi][ni]);
    __syncthreads();
  }

#pragma unroll
  for (int mi = 0; mi < 4; mi++)
#pragma unroll
    for (int ni = 0; ni < 4; ni++)
#pragma unroll
      for (int r = 0; r < 4; r++) {
        int m = m0 + wr * 64 + mi * 16 + lg * 4 + r;
        int n = n0 + wc * 64 + ni * 16 + l15;
        C[(size_t)m * 1024 + n] = acc[mi][ni][r];
      }
}

// Flash attention, causal, exp2 domain (Q pre-scaled by 0.125*log2e).
// Swapped QK^T (lane-local softmax, q=l15), defer-max rescale (THR=8).
__global__ __launch_bounds__(256, 3) void attn_fwd(const bf16* __restrict__ Q,
                                                   const bf16* __restrict__ K,
                                                   const bf16* __restrict__ Vt,
                                                   bf16* __restrict__ O) {
  __shared__ __align__(16) bf16 lK[2][64 * 64];
  __shared__ __align__(16) bf16 lV[2][64 * 64];
  __shared__ __align__(16) bf16 lP[4][32 * 64];
  const int tid = threadIdx.x, lane = tid & 63, w = tid >> 6;
  const int l15 = lane & 15, lg = lane >> 4;
  const int bh = blockIdx.x;
  const int qb = 15 - blockIdx.y;  // LPT: heavy blocks first
  const int q0 = qb * 128 + w * 32;
  const bf16* Qb = Q + (size_t)bh * S_ * 64;
  const bf16* Kb = K + (size_t)bh * S_ * 64;
  const bf16* Vb = Vt + (size_t)bh * 64 * S_;
  bf16* Pw = lP[w];

  short8 qf[2][2];
#pragma unroll
  for (int mi = 0; mi < 2; mi++)
#pragma unroll
    for (int kd = 0; kd < 2; kd++)
      qf[mi][kd] = *(const short8*)&Qb[(size_t)(q0 + mi * 16 + l15) * 64 + kd * 32 + lg * 8];

  f32x4 zero = {0.f, 0.f, 0.f, 0.f};
  f32x4 acc[2][4];
  float mr[2], lr[2];
#pragma unroll
  for (int mi = 0; mi < 2; mi++) {
    mr[mi] = -1e9f;
    lr[mi] = 0.f;
#pragma unroll
    for (int ni = 0; ni < 4; ni++) acc[mi][ni] = zero;
  }

  const int nch = (qb + 1) * 2;

#define STAGE(buf, c)                                                                   \
  {                                                                                     \
    _Pragma("unroll") for (int i = 0; i < 2; ++i) {                                     \
      int t2 = i * 256 + tid;                                                           \
      int row = t2 >> 3;                                                                \
      int cb = ((t2 & 7) * 16) ^ ((row & 7) << 4);                                      \
      gload16((char*)lK[buf] + t2 * 16, (const char*)Kb + (size_t)((c) * 64 + row) * 128 + cb); \
      gload16((char*)lV[buf] + t2 * 16, (const char*)Vb + (size_t)row * 4096 + (size_t)(c) * 128 + cb); \
    }                                                                                   \
  }

  STAGE(0, 0);
  int cur = 0;
  for (int c = 0; c < nch; ++c) {
    __builtin_amdgcn_s_barrier();
    if (c + 1 < nch) {
      STAGE(cur ^ 1, c + 1);
      asm volatile("s_waitcnt vmcnt(4)" ::: "memory");
    } else {
      asm volatile("s_waitcnt vmcnt(0)" ::: "memory");
    }
    __builtin_amdgcn_s_barrier();

    if (c * 64 <= q0 + 31) {
      const int c0 = c * 64;
      f32x4 sc[2][4];
#pragma unroll
      for (int mi = 0; mi < 2; mi++)
#pragma unroll
        for (int ch = 0; ch < 4; ch++) sc[mi][ch] = zero;
      const char* Kc = (const char*)lK[cur];
      __builtin_amdgcn_s_setprio(1);
#pragma unroll
      for (int kd = 0; kd < 2; ++kd)
#pragma unroll
        for (int ch = 0; ch < 4; ++ch) {
          short8 kf = *(const short8*)(Kc + (ch * 16 + l15) * 128 + ((kd * 64 + lg * 16) ^ ((l15 & 7) << 4)));
          sc[0][ch] = MFMA16(kf, qf[0][kd], sc[0][ch]);  // swapped: D[kv][q]
          sc[1][ch] = MFMA16(kf, qf[1][kd], sc[1][ch]);
        }
      __builtin_amdgcn_s_setprio(0);

      if (c0 + 63 > q0) {
#pragma unroll
        for (int mi = 0; mi < 2; mi++) {
          int q = q0 + mi * 16 + l15;
#pragma unroll
          for (int ch = 0; ch < 4; ch++)
#pragma unroll
            for (int r = 0; r < 4; r++) {
              int kv = c0 + ch * 16 + lg * 4 + r;
              if (kv > q) sc[mi][ch][r] = -1e9f;
            }
        }
      }

#pragma unroll
      for (int mi = 0; mi < 2; mi++) {
        float v0 = fmaxf(fmaxf(sc[mi][0][0], sc[mi][0][1]), fmaxf(sc[mi][0][2], sc[mi][0][3]));
        float v1 = fmaxf(fmaxf(sc[mi][1][0], sc[mi][1][1]), fmaxf(sc[mi][1][2], sc[mi][1][3]));
        float v2 = fmaxf(fmaxf(sc[mi][2][0], sc[mi][2][1]), fmaxf(sc[mi][2][2], sc[mi][2][3]));
        float v3 = fmaxf(fmaxf(sc[mi][3][0], sc[mi][3][1]), fmaxf(sc[mi][3][2], sc[mi][3][3]));
        float vmax = fmaxf(fmaxf(v0, v1), fmaxf(v2, v3));
        vmax = fmaxf(vmax, __shfl_xor(vmax, 16));
        vmax = fmaxf(vmax, __shfl_xor(vmax, 32));
        // defer-max: only rescale when some row's max grew past THR=8 (exp2 domain)
        if (!__all(vmax <= mr[mi] + 8.f)) {
          float mn = fmaxf(mr[mi], vmax);
          float corr = exp2f(mr[mi] - mn);
          mr[mi] = mn;
          lr[mi] *= corr;
#pragma unroll
          for (int r = 0; r < 4; r++) {
            float cr = __shfl(corr, (lane & 48) | (((lane >> 4) << 2) + r));
#pragma unroll
            for (int ni = 0; ni < 4; ni++) acc[mi][ni][r] *= cr;
          }
        }
        float ps = 0.f;
#pragma unroll
        for (int ch = 0; ch < 4; ch++)
#pragma unroll
          for (int r = 0; r < 4; r++) {
            float p = exp2f(sc[mi][ch][r] - mr[mi]);
            sc[mi][ch][r] = p;
            ps += p;
          }
        ps += __shfl_xor(ps, 16);
        ps += __shfl_xor(ps, 32);
        lr[mi] += ps;
        int row = mi * 16 + l15;
        char* Pb = (char*)Pw + row * 128;
        int sw = (row & 7) << 4;
#pragma unroll
        for (int ch = 0; ch < 4; ch++) {
          u32 d0 = pk2(sc[mi][ch][0], sc[mi][ch][1]);
          u32 d1 = pk2(sc[mi][ch][2], sc[mi][ch][3]);
          uint2 dd = {d0, d1};
          *(uint2*)(Pb + ((ch * 32 + lg * 8) ^ sw)) = dd;
        }
      }

      asm volatile("s_waitcnt lgkmcnt(0)" ::: "memory");
      const char* Vc = (const char*)lV[cur];
      __builtin_amdgcn_s_setprio(1);
#pragma unroll
      for (int kd = 0; kd < 2; ++kd) {
        short8 pf[2];
#pragma unroll
        for (int mi = 0; mi < 2; mi++)
          pf[mi] = *(const short8*)((const char*)Pw + (mi * 16 + l15) * 128 +
                                    ((kd * 64 + lg * 16) ^ ((l15 & 7) << 4)));
#pragma unroll
        for (int ni = 0; ni < 4; ++ni) {
          short8 vf = *(const short8*)(Vc + (ni * 16 + l15) * 128 + ((kd * 64 + lg * 16) ^ ((l15 & 7) << 4)));
          acc[0][ni] = MFMA16(pf[0], vf, acc[0][ni]);
          acc[1][ni] = MFMA16(pf[1], vf, acc[1][ni]);
        }
      }
      __builtin_amdgcn_s_setprio(0);
    }
    cur ^= 1;
  }
#undef STAGE

  const int b = bh >> 4, h = bh & 15;
#pragma unroll
  for (int mi = 0; mi < 2; mi++) {
    float lrr[4];
#pragma unroll
    for (int r = 0; r < 4; r++)
      lrr[r] = __shfl(lr[mi], (lane & 48) | (((lane >> 4) << 2) + r));
#pragma unroll
    for (int ni = 0; ni < 4; ni++)
#pragma unroll
      for (int r = 0; r < 4; r++) {
        int q = q0 + mi * 16 + lg * 4 + r;
        size_t idx = ((size_t)(b * 2048 + q)) * 1024 + h * 64 + ni * 16 + l15;
        O[idx] = __float2bfloat16(acc[mi][ni][r] / lrr[r]);
      }
  }
}

extern "C" void kernel_launch(void* const* d_in, const int* in_sizes, int n_in,
                              void* d_out, int out_size, void* d_ws, size_t ws_size,
                              hipStream_t stream) {
  const float* x = (const float*)d_in[0];
  const float* wq = (const float*)d_in[1];
  const float* wk = (const float*)d_in[2];
  const float* wv = (const float*)d_in[3];
  const float* wo = (const float*)d_in[4];
  float* out = (float*)d_out;

  bf16* xb = (bf16*)d_ws;  // x bf16; becomes AO after attn
  bf16* Qw = xb + SZ;      // QKV contiguous: Qw, Kw=Qw+SZ, Vw=Qw+2SZ
  bf16* AO = xb;
  bf16* wqkv = (bf16*)d_out;  // 3 weight matrices, dead before final GEMM writes out

  const bool ws_has_wo = ws_size >= (4 * SZ + WSZ) * sizeof(bf16);
  bf16* wob = ws_has_wo ? (xb + 4 * SZ) : Qw;  // fallback: Qw (dead after attn)

  dim3 blk(256);
  hipLaunchKernelGGL(cvt_f32_bf16, dim3(2048), blk, 0, stream, x, xb, (int)(SZ / 4));
  hipLaunchKernelGGL(cvt_w, dim3(1024), blk, 0, stream, wq, wk, wv, wo, wqkv, wob,
                     ws_has_wo ? 4 : 3);
  hipLaunchKernelGGL(qkv_gemm, dim3(64, 24), blk, 0, stream, xb, wqkv, Qw);
  hipLaunchKernelGGL(attn_fwd, dim3(64, 16), blk, 0, stream, Qw, Qw + SZ, Qw + 2 * SZ, AO);
  if (!ws_has_wo)
    hipLaunchKernelGGL(cvt_f32_bf16, dim3(512), blk, 0, stream, wo, wob, (int)(WSZ / 4));
  hipLaunchKernelGGL(gemm_out, dim3(64, 8), blk, 0, stream, AO, wob, out);
}

// Round 6
// 259.745 us; speedup vs baseline: 1.0848x; 1.0848x over previous
//
#include <hip/hip_runtime.h>
#include <hip/hip_bf16.h>

typedef __hip_bfloat16 bf16;
typedef __attribute__((ext_vector_type(8))) short short8;
typedef __attribute__((ext_vector_type(4))) short short4_t;
typedef __attribute__((ext_vector_type(4))) float f32x4;
typedef unsigned int u32;

#define MFMA16(a, b, c) __builtin_amdgcn_mfma_f32_16x16x32_bf16(a, b, c, 0, 0, 0)

#if __has_builtin(__builtin_amdgcn_exp2f)
#define EXP2(x) __builtin_amdgcn_exp2f(x)
#else
#define EXP2(x) __expf((x) * 0.6931471805599453f)
#endif

static constexpr int S_ = 2048, D_ = 1024, M_ = 8192;
static constexpr size_t SZ = (size_t)M_ * D_;   // 8.39M elems
static constexpr size_t WSZ = (size_t)D_ * D_;  // 1.05M elems
static constexpr float QSCALE = 0.125f * 1.4426950408889634f;  // 1/sqrt(64) * log2(e)

__device__ __forceinline__ void gload16(void* lds, const void* g) {
  __builtin_amdgcn_global_load_lds((const __attribute__((address_space(1))) void*)g,
                                   (__attribute__((address_space(3))) void*)lds, 16, 0, 0);
}

__device__ __forceinline__ short4_t cvt4(const float4 v) {
  short4_t r;
  r[0] = (short)__bfloat16_as_ushort(__float2bfloat16(v.x));
  r[1] = (short)__bfloat16_as_ushort(__float2bfloat16(v.y));
  r[2] = (short)__bfloat16_as_ushort(__float2bfloat16(v.z));
  r[3] = (short)__bfloat16_as_ushort(__float2bfloat16(v.w));
  return r;
}

__device__ __forceinline__ u32 pk2(float a, float b) {
  return (u32)__bfloat16_as_ushort(__float2bfloat16(a)) |
         ((u32)__bfloat16_as_ushort(__float2bfloat16(b)) << 16);
}

__global__ __launch_bounds__(256) void cvt_f32_bf16(const float* __restrict__ in,
                                                    bf16* __restrict__ out, int n4) {
  int stride = gridDim.x * 256;
  for (int i = blockIdx.x * 256 + threadIdx.x; i < n4; i += stride) {
    float4 v = ((const float4*)in)[i];
    *(short4_t*)&out[(size_t)i * 4] = cvt4(v);
  }
}

// single pass: x -> xb, wq/wk/wv -> wqkv (contiguous), optional wo -> wob
__global__ __launch_bounds__(256) void cvt_all(const float* __restrict__ x,
                                               const float* __restrict__ wq,
                                               const float* __restrict__ wk,
                                               const float* __restrict__ wv,
                                               const float* __restrict__ wo,
                                               bf16* __restrict__ xb,
                                               bf16* __restrict__ wqkv,
                                               bf16* __restrict__ wob, int nseg) {
  const int X4 = (int)(SZ / 4);
  const int per = 1 << 18;  // WSZ/4
  int total = X4 + nseg * per;
  for (int i = blockIdx.x * 256 + threadIdx.x; i < total; i += gridDim.x * 256) {
    const float* s;
    bf16* d;
    int off;
    if (i < X4) {
      s = x; d = xb; off = i;
    } else {
      int j = i - X4;
      int seg = j >> 18;
      off = j & (per - 1);
      s = (seg == 0) ? wq : (seg == 1) ? wk : (seg == 2) ? wv : wo;
      d = (seg < 3) ? (wqkv + ((size_t)seg << 20)) : wob;
    }
    float4 v = ((const float4*)s)[off];
    *(short4_t*)&d[(size_t)off * 4] = cvt4(v);
  }
}

// Fused QKV projection: by in [0,24): mat = by>>3 (0=Q,1=K,2=V), n0 = (by&7)*128.
// Q scaled by QSCALE; Q,K -> [B][H][S][64]; V -> [B][H][64][S] via swapped-operand MFMA
// (computes D^T with identical fragments -> contiguous stores along s).
__global__ __launch_bounds__(256) void qkv_gemm(const bf16* __restrict__ A,
                                                const bf16* __restrict__ Wqkv,
                                                bf16* __restrict__ QKV) {
  __shared__ __align__(16) bf16 lA[128 * 32];
  __shared__ __align__(16) bf16 lB[128 * 32];
  const int tid = threadIdx.x, lane = tid & 63, w = tid >> 6;
  const int wr = w >> 1, wc = w & 1;
  const int m0 = blockIdx.x * 128;
  const int mat = blockIdx.y >> 3, n0 = (blockIdx.y & 7) * 128;
  const bf16* W = Wqkv + (size_t)mat * WSZ;
  bf16* C = QKV + (size_t)mat * SZ;
  const int l15 = lane & 15, lg = lane >> 4;

  f32x4 zero = {0.f, 0.f, 0.f, 0.f};
  f32x4 acc[4][4];
#pragma unroll
  for (int i = 0; i < 4; i++)
#pragma unroll
    for (int j = 0; j < 4; j++) acc[i][j] = zero;

  for (int kt = 0; kt < 32; ++kt) {
    const int k0 = kt * 32;
#pragma unroll
    for (int i = 0; i < 2; ++i) {
      int c = i * 256 + tid;
      int row = c >> 2, col = (c & 3) * 8;
      gload16(&lA[c * 8], &A[(size_t)(m0 + row) * 1024 + k0 + col]);
      gload16(&lB[c * 8], &W[(size_t)(n0 + row) * 1024 + k0 + col]);
    }
    __syncthreads();

    short8 af[4], bfr[4];
#pragma unroll
    for (int mi = 0; mi < 4; mi++)
      af[mi] = *(const short8*)&lA[(wr * 64 + mi * 16 + l15) * 32 + lg * 8];
#pragma unroll
    for (int ni = 0; ni < 4; ni++)
      bfr[ni] = *(const short8*)&lB[(wc * 64 + ni * 16 + l15) * 32 + lg * 8];
    if (mat == 2) {
#pragma unroll
      for (int mi = 0; mi < 4; mi++)
#pragma unroll
        for (int ni = 0; ni < 4; ni++) acc[mi][ni] = MFMA16(bfr[ni], af[mi], acc[mi][ni]);
    } else {
#pragma unroll
      for (int mi = 0; mi < 4; mi++)
#pragma unroll
        for (int ni = 0; ni < 4; ni++) acc[mi][ni] = MFMA16(af[mi], bfr[ni], acc[mi][ni]);
    }
    __syncthreads();
  }

  if (mat == 2) {
    // D^T layout: col(l15) = m (=s), row(lg*4+r) = n (=h*64+dh)
#pragma unroll
    for (int mi = 0; mi < 4; mi++)
#pragma unroll
      for (int ni = 0; ni < 4; ni++)
#pragma unroll
        for (int r = 0; r < 4; r++) {
          int m = m0 + wr * 64 + mi * 16 + l15;
          int n = n0 + wc * 64 + ni * 16 + lg * 4 + r;
          int b = m >> 11, s = m & 2047, h = n >> 6, dh = n & 63;
          size_t idx = ((size_t)((b << 4) + h) * 64 + dh) * 2048 + s;
          C[idx] = __float2bfloat16(acc[mi][ni][r]);
        }
  } else {
    const float scale = (mat == 0) ? QSCALE : 1.0f;
#pragma unroll
    for (int mi = 0; mi < 4; mi++)
#pragma unroll
      for (int ni = 0; ni < 4; ni++)
#pragma unroll
        for (int r = 0; r < 4; r++) {
          int m = m0 + wr * 64 + mi * 16 + lg * 4 + r;
          int n = n0 + wc * 64 + ni * 16 + l15;
          int b = m >> 11, s = m & 2047, h = n >> 6, dh = n & 63;
          size_t idx = ((size_t)((b << 4) + h) * 2048 + s) * 64 + dh;
          C[idx] = __float2bfloat16(acc[mi][ni][r] * scale);
        }
  }
}

// Output projection: C[m][n] f32 = sum_k AO[m][k] * Wo[n][k]
__global__ __launch_bounds__(256) void gemm_out(const bf16* __restrict__ A,
                                                const bf16* __restrict__ W,
                                                float* __restrict__ C) {
  __shared__ __align__(16) bf16 lA[128 * 32];
  __shared__ __align__(16) bf16 lB[128 * 32];
  const int tid = threadIdx.x, lane = tid & 63, w = tid >> 6;
  const int wr = w >> 1, wc = w & 1;
  const int m0 = blockIdx.x * 128, n0 = blockIdx.y * 128;
  const int l15 = lane & 15, lg = lane >> 4;

  f32x4 zero = {0.f, 0.f, 0.f, 0.f};
  f32x4 acc[4][4];
#pragma unroll
  for (int i = 0; i < 4; i++)
#pragma unroll
    for (int j = 0; j < 4; j++) acc[i][j] = zero;

  for (int kt = 0; kt < 32; ++kt) {
    const int k0 = kt * 32;
#pragma unroll
    for (int i = 0; i < 2; ++i) {
      int c = i * 256 + tid;
      int row = c >> 2, col = (c & 3) * 8;
      gload16(&lA[c * 8], &A[(size_t)(m0 + row) * 1024 + k0 + col]);
      gload16(&lB[c * 8], &W[(size_t)(n0 + row) * 1024 + k0 + col]);
    }
    __syncthreads();

    short8 af[4], bfr[4];
#pragma unroll
    for (int mi = 0; mi < 4; mi++)
      af[mi] = *(const short8*)&lA[(wr * 64 + mi * 16 + l15) * 32 + lg * 8];
#pragma unroll
    for (int ni = 0; ni < 4; ni++)
      bfr[ni] = *(const short8*)&lB[(wc * 64 + ni * 16 + l15) * 32 + lg * 8];
#pragma unroll
    for (int mi = 0; mi < 4; mi++)
#pragma unroll
      for (int ni = 0; ni < 4; ni++) acc[mi][ni] = MFMA16(af[mi], bfr[ni], acc[mi][ni]);
    __syncthreads();
  }

#pragma unroll
  for (int mi = 0; mi < 4; mi++)
#pragma unroll
    for (int ni = 0; ni < 4; ni++)
#pragma unroll
      for (int r = 0; r < 4; r++) {
        int m = m0 + wr * 64 + mi * 16 + lg * 4 + r;
        int n = n0 + wc * 64 + ni * 16 + l15;
        C[(size_t)m * 1024 + n] = acc[mi][ni][r];
      }
}

// Flash attention, causal, exp2 domain (Q pre-scaled by 0.125*log2e), native v_exp.
// Swapped QK^T (lane-local softmax, q=l15), defer-max rescale (THR=8).
__global__ __launch_bounds__(256, 3) void attn_fwd(const bf16* __restrict__ Q,
                                                   const bf16* __restrict__ K,
                                                   const bf16* __restrict__ Vt,
                                                   bf16* __restrict__ O) {
  __shared__ __align__(16) bf16 lK[2][64 * 64];
  __shared__ __align__(16) bf16 lV[2][64 * 64];
  __shared__ __align__(16) bf16 lP[4][32 * 64];
  const int tid = threadIdx.x, lane = tid & 63, w = tid >> 6;
  const int l15 = lane & 15, lg = lane >> 4;
  const int bh = blockIdx.x;
  const int qb = 15 - blockIdx.y;  // LPT: heavy blocks first
  const int q0 = qb * 128 + w * 32;
  const bf16* Qb = Q + (size_t)bh * S_ * 64;
  const bf16* Kb = K + (size_t)bh * S_ * 64;
  const bf16* Vb = Vt + (size_t)bh * 64 * S_;
  bf16* Pw = lP[w];

  short8 qf[2][2];
#pragma unroll
  for (int mi = 0; mi < 2; mi++)
#pragma unroll
    for (int kd = 0; kd < 2; kd++)
      qf[mi][kd] = *(const short8*)&Qb[(size_t)(q0 + mi * 16 + l15) * 64 + kd * 32 + lg * 8];

  f32x4 zero = {0.f, 0.f, 0.f, 0.f};
  f32x4 acc[2][4];
  float mr[2], lr[2];
#pragma unroll
  for (int mi = 0; mi < 2; mi++) {
    mr[mi] = -1e9f;
    lr[mi] = 0.f;
#pragma unroll
    for (int ni = 0; ni < 4; ni++) acc[mi][ni] = zero;
  }

  const int nch = (qb + 1) * 2;

#define STAGE(buf, c)                                                                   \
  {                                                                                     \
    _Pragma("unroll") for (int i = 0; i < 2; ++i) {                                     \
      int t2 = i * 256 + tid;                                                           \
      int row = t2 >> 3;                                                                \
      int cb = ((t2 & 7) * 16) ^ ((row & 7) << 4);                                      \
      gload16((char*)lK[buf] + t2 * 16, (const char*)Kb + (size_t)((c) * 64 + row) * 128 + cb); \
      gload16((char*)lV[buf] + t2 * 16, (const char*)Vb + (size_t)row * 4096 + (size_t)(c) * 128 + cb); \
    }                                                                                   \
  }

  STAGE(0, 0);
  int cur = 0;
  for (int c = 0; c < nch; ++c) {
    __builtin_amdgcn_s_barrier();
    if (c + 1 < nch) {
      STAGE(cur ^ 1, c + 1);
      asm volatile("s_waitcnt vmcnt(4)" ::: "memory");
    } else {
      asm volatile("s_waitcnt vmcnt(0)" ::: "memory");
    }
    __builtin_amdgcn_s_barrier();

    if (c * 64 <= q0 + 31) {
      const int c0 = c * 64;
      f32x4 sc[2][4];
#pragma unroll
      for (int mi = 0; mi < 2; mi++)
#pragma unroll
        for (int ch = 0; ch < 4; ch++) sc[mi][ch] = zero;
      const char* Kc = (const char*)lK[cur];
      __builtin_amdgcn_s_setprio(1);
#pragma unroll
      for (int kd = 0; kd < 2; ++kd)
#pragma unroll
        for (int ch = 0; ch < 4; ++ch) {
          short8 kf = *(const short8*)(Kc + (ch * 16 + l15) * 128 + ((kd * 64 + lg * 16) ^ ((l15 & 7) << 4)));
          sc[0][ch] = MFMA16(kf, qf[0][kd], sc[0][ch]);  // swapped: D[kv][q]
          sc[1][ch] = MFMA16(kf, qf[1][kd], sc[1][ch]);
        }
      __builtin_amdgcn_s_setprio(0);

      if (c0 + 63 > q0) {
#pragma unroll
        for (int mi = 0; mi < 2; mi++) {
          int q = q0 + mi * 16 + l15;
#pragma unroll
          for (int ch = 0; ch < 4; ch++)
#pragma unroll
            for (int r = 0; r < 4; r++) {
              int kv = c0 + ch * 16 + lg * 4 + r;
              if (kv > q) sc[mi][ch][r] = -1e9f;
            }
        }
      }

#pragma unroll
      for (int mi = 0; mi < 2; mi++) {
        float v0 = fmaxf(fmaxf(sc[mi][0][0], sc[mi][0][1]), fmaxf(sc[mi][0][2], sc[mi][0][3]));
        float v1 = fmaxf(fmaxf(sc[mi][1][0], sc[mi][1][1]), fmaxf(sc[mi][1][2], sc[mi][1][3]));
        float v2 = fmaxf(fmaxf(sc[mi][2][0], sc[mi][2][1]), fmaxf(sc[mi][2][2], sc[mi][2][3]));
        float v3 = fmaxf(fmaxf(sc[mi][3][0], sc[mi][3][1]), fmaxf(sc[mi][3][2], sc[mi][3][3]));
        float vmax = fmaxf(fmaxf(v0, v1), fmaxf(v2, v3));
        vmax = fmaxf(vmax, __shfl_xor(vmax, 16));
        vmax = fmaxf(vmax, __shfl_xor(vmax, 32));
        // defer-max: only rescale when some row's max grew past THR=8 (exp2 domain)
        if (!__all(vmax <= mr[mi] + 8.f)) {
          float mn = fmaxf(mr[mi], vmax);
          float corr = EXP2(mr[mi] - mn);
          mr[mi] = mn;
          lr[mi] *= corr;
#pragma unroll
          for (int r = 0; r < 4; r++) {
            float cr = __shfl(corr, (lane & 48) | (((lane >> 4) << 2) + r));
#pragma unroll
            for (int ni = 0; ni < 4; ni++) acc[mi][ni][r] *= cr;
          }
        }
        float ps0 = 0.f, ps1 = 0.f, ps2 = 0.f, ps3 = 0.f;
#pragma unroll
        for (int ch = 0; ch < 4; ch++) {
          float p0 = EXP2(sc[mi][ch][0] - mr[mi]);
          float p1 = EXP2(sc[mi][ch][1] - mr[mi]);
          float p2 = EXP2(sc[mi][ch][2] - mr[mi]);
          float p3 = EXP2(sc[mi][ch][3] - mr[mi]);
          sc[mi][ch][0] = p0; sc[mi][ch][1] = p1; sc[mi][ch][2] = p2; sc[mi][ch][3] = p3;
          ps0 += p0; ps1 += p1; ps2 += p2; ps3 += p3;
        }
        float ps = (ps0 + ps1) + (ps2 + ps3);
        ps += __shfl_xor(ps, 16);
        ps += __shfl_xor(ps, 32);
        lr[mi] += ps;
        int row = mi * 16 + l15;
        char* Pb = (char*)Pw + row * 128;
        int sw = (row & 7) << 4;
#pragma unroll
        for (int ch = 0; ch < 4; ch++) {
          u32 d0 = pk2(sc[mi][ch][0], sc[mi][ch][1]);
          u32 d1 = pk2(sc[mi][ch][2], sc[mi][ch][3]);
          uint2 dd = {d0, d1};
          *(uint2*)(Pb + ((ch * 32 + lg * 8) ^ sw)) = dd;
        }
      }

      asm volatile("s_waitcnt lgkmcnt(0)" ::: "memory");
      const char* Vc = (const char*)lV[cur];
      __builtin_amdgcn_s_setprio(1);
#pragma unroll
      for (int kd = 0; kd < 2; ++kd) {
        short8 pf[2];
#pragma unroll
        for (int mi = 0; mi < 2; mi++)
          pf[mi] = *(const short8*)((const char*)Pw + (mi * 16 + l15) * 128 +
                                    ((kd * 64 + lg * 16) ^ ((l15 & 7) << 4)));
#pragma unroll
        for (int ni = 0; ni < 4; ++ni) {
          short8 vf = *(const short8*)(Vc + (ni * 16 + l15) * 128 + ((kd * 64 + lg * 16) ^ ((l15 & 7) << 4)));
          acc[0][ni] = MFMA16(pf[0], vf, acc[0][ni]);
          acc[1][ni] = MFMA16(pf[1], vf, acc[1][ni]);
        }
      }
      __builtin_amdgcn_s_setprio(0);
    }
    cur ^= 1;
  }
#undef STAGE

  const int b = bh >> 4, h = bh & 15;
#pragma unroll
  for (int mi = 0; mi < 2; mi++) {
    float lrr[4];
#pragma unroll
    for (int r = 0; r < 4; r++)
      lrr[r] = __shfl(lr[mi], (lane & 48) | (((lane >> 4) << 2) + r));
#pragma unroll
    for (int ni = 0; ni < 4; ni++)
#pragma unroll
      for (int r = 0; r < 4; r++) {
        int q = q0 + mi * 16 + lg * 4 + r;
        size_t idx = ((size_t)(b * 2048 + q)) * 1024 + h * 64 + ni * 16 + l15;
        O[idx] = __float2bfloat16(acc[mi][ni][r] / lrr[r]);
      }
  }
}

extern "C" void kernel_launch(void* const* d_in, const int* in_sizes, int n_in,
                              void* d_out, int out_size, void* d_ws, size_t ws_size,
                              hipStream_t stream) {
  const float* x = (const float*)d_in[0];
  const float* wq = (const float*)d_in[1];
  const float* wk = (const float*)d_in[2];
  const float* wv = (const float*)d_in[3];
  const float* wo = (const float*)d_in[4];
  float* out = (float*)d_out;

  bf16* xb = (bf16*)d_ws;  // x bf16; becomes AO after attn
  bf16* Qw = xb + SZ;      // QKV contiguous: Qw, Kw=Qw+SZ, Vw=Qw+2SZ
  bf16* AO = xb;
  bf16* wqkv = (bf16*)d_out;  // 3 weight matrices, dead before final GEMM writes out

  const bool ws_has_wo = ws_size >= (4 * SZ + WSZ) * sizeof(bf16);
  bf16* wob = ws_has_wo ? (xb + 4 * SZ) : Qw;  // fallback: Qw (dead after attn)

  dim3 blk(256);
  hipLaunchKernelGGL(cvt_all, dim3(2048), blk, 0, stream, x, wq, wk, wv, wo, xb, wqkv, wob,
                     ws_has_wo ? 4 : 3);
  hipLaunchKernelGGL(qkv_gemm, dim3(64, 24), blk, 0, stream, xb, wqkv, Qw);
  hipLaunchKernelGGL(attn_fwd, dim3(64, 16), blk, 0, stream, Qw, Qw + SZ, Qw + 2 * SZ, AO);
  if (!ws_has_wo)
    hipLaunchKernelGGL(cvt_f32_bf16, dim3(512), blk, 0, stream, wo, wob, (int)(WSZ / 4));
  hipLaunchKernelGGL(gemm_out, dim3(64, 8), blk, 0, stream, AO, wob, out);
}